// Round 1
// baseline (276.070 us; speedup 1.0000x reference)
//
#include <hip/hip_runtime.h>
#include <hip/hip_bf16.h>
#include <math.h>

#define HID 512
#define HEADS 4
#define OUTF 128

typedef __attribute__((ext_vector_type(8))) _Float16 f16x8_t;   // 8 f16 in 4 VGPRs
typedef __attribute__((ext_vector_type(4))) _Float16 f16x4_t;
typedef __attribute__((ext_vector_type(4))) float f32x4_t;

// ---------------------------------------------------------------------------
// helpers
// ---------------------------------------------------------------------------
__device__ __forceinline__ void gl_lds16(const void* g, void* l) {
    __builtin_amdgcn_global_load_lds(
        (const __attribute__((address_space(1))) void*)g,
        (__attribute__((address_space(3))) void*)l, 16, 0, 0);
}

// stage a [128 rows][32 f16] plane into LDS with XOR-chunk swizzle
// (chunk ^= (row>>1)&3), 512 threads: exactly 1 chunk per thread.
// LDS byte gci*16 holds row (gci>>2), logical chunk (gci&3) ^ ((row>>1)&3).
// 2-way-max bank aliasing on the ds_read_b128 side (quarter-wave analysis):
// bank group = (row&1, chunk^swz) -> 8 combos over 16 rows = 2 lanes each.
__device__ __forceinline__ void stage_plane32(const _Float16* g, int strideE,
    int rbase, int rmax, char* plane, int wave, int lane)
{
    int gci = wave * 64 + lane;              // 0..511
    int r = gci >> 2, c = gci & 3;
    int rg = rbase + r; if (rg > rmax) rg = rmax;
    const char* s = (const char*)(g + (size_t)rg * strideE) + ((c ^ ((r >> 1) & 3)) << 4);
    char* d = plane + wave * 1024;           // wave-uniform base (+lane*16 implicit)
    gl_lds16(s, d);
}

// ---------------------------------------------------------------------------
// fp32 -> fp16 streaming convert
// ---------------------------------------------------------------------------
__global__ __launch_bounds__(256) void conv16_kernel(const float* __restrict__ in,
    _Float16* __restrict__ o, int nquad)
{
    int stride = gridDim.x * 256;
    for (int i = blockIdx.x * 256 + threadIdx.x; i < nquad; i += stride) {
        float4 v = *(const float4*)&in[(size_t)i * 4];
        f16x4_t ov;
        ov[0] = (_Float16)v.x; ov[1] = (_Float16)v.y;
        ov[2] = (_Float16)v.z; ov[3] = (_Float16)v.w;
        *(f16x4_t*)&o[(size_t)i * 4] = ov;
    }
}

// ---------------------------------------------------------------------------
// W prep: transpose [K][NC] fp32 -> [NC][K] fp16
// ---------------------------------------------------------------------------
__global__ __launch_bounds__(256) void prep_w(const float* __restrict__ W,
    _Float16* __restrict__ Wt, int K, int NC)
{
    __shared__ float tile[32][33];
    const int k0 = blockIdx.x * 32, n0 = blockIdx.y * 32;
    const int t = threadIdx.x;
    {
        int r = t >> 3, c4 = (t & 7) * 4;
        float4 v = *(const float4*)&W[(size_t)(k0 + r) * NC + n0 + c4];
        tile[r][c4] = v.x; tile[r][c4 + 1] = v.y;
        tile[r][c4 + 2] = v.z; tile[r][c4 + 3] = v.w;
    }
    __syncthreads();
    int n = t >> 3, kc = (t & 7) * 4;
#pragma unroll
    for (int i = 0; i < 4; ++i)
        Wt[(size_t)(n0 + n) * K + k0 + kc + i] = (_Float16)tile[kc + i][n];
}

// ---------------------------------------------------------------------------
// fp16 MFMA GEMM: C[M][NCOL] = A[M][K] @ B[K][NCOL].
// 8 waves (512 thr), tile 128x128, BK=32, wave tile 64x32 (acc 4x2 frags).
// Double-buffered K-loop, one barrier per K-step. LDS 32 KB -> 3 blocks/CU
// (launch_bounds(512,6)) so the 628-block grids are fully co-resident
// (kills the 2-phase tail that showed as OccupancyPercent ~29).
// EPI 1: fused bias+ELU. OUT16: fp16 C. ELER 1: emit el/er (head=blockIdx.x).
// ---------------------------------------------------------------------------
template<int EPI, int OUT16, int ELER>
__global__ __launch_bounds__(512, 6) void gemm_f16(
    const _Float16* __restrict__ Af, const _Float16* __restrict__ Bt,
    const float* __restrict__ bias,
    const float* __restrict__ attl, const float* __restrict__ attr,
    float* __restrict__ elp, float* __restrict__ erp,
    void* __restrict__ Cout, int M, int K, int NCOL, int ldC)
{
    __shared__ char lds[32768];
    const int tid = threadIdx.x;
    const int wave = tid >> 6, lane = tid & 63;
    const int wm = wave >> 2, wn = wave & 3;      // 2 x 4 wave grid
    const int bm = blockIdx.y * 128, bn = blockIdx.x * 128;
    const int l15 = lane & 15, l4 = lane >> 4;
    const int swz = (l15 >> 1) & 3;

    f32x4_t acc[4][2];
#pragma unroll
    for (int i = 0; i < 4; ++i)
#pragma unroll
        for (int j = 0; j < 2; ++j) acc[i][j] = (f32x4_t){0.f, 0.f, 0.f, 0.f};

    const int nt = K >> 5;                         // BK = 32
    stage_plane32(Af, K, bm, M - 1, lds, wave, lane);
    stage_plane32(Bt, K, bn, NCOL - 1, lds + 8192, wave, lane);
    __syncthreads();

    for (int t = 0; t < nt; ++t) {
        char* AH = lds + (t & 1) * 16384;
        char* BH = AH + 8192;
        if (t + 1 < nt) {
            char* AHn = lds + ((t + 1) & 1) * 16384;
            stage_plane32(Af + (t + 1) * 32, K, bm, M - 1, AHn, wave, lane);
            stage_plane32(Bt + (t + 1) * 32, K, bn, NCOL - 1, AHn + 8192, wave, lane);
        }
        f16x8_t fa[4], fb[2];
#pragma unroll
        for (int mf = 0; mf < 4; ++mf) {
            int row = wm * 64 + mf * 16 + l15;
            fa[mf] = *(const f16x8_t*)(AH + row * 64 + ((l4 ^ swz) << 4));
        }
#pragma unroll
        for (int nf = 0; nf < 2; ++nf) {
            int rn = wn * 32 + nf * 16 + l15;
            fb[nf] = *(const f16x8_t*)(BH + rn * 64 + ((l4 ^ swz) << 4));
        }
#pragma unroll
        for (int mf = 0; mf < 4; ++mf)
#pragma unroll
            for (int nf = 0; nf < 2; ++nf)
                acc[mf][nf] = __builtin_amdgcn_mfma_f32_16x16x32_f16(fa[mf], fb[nf], acc[mf][nf], 0, 0, 0);
        __syncthreads();
    }
    // epilogue: C/D layout col=lane&15, row=(lane>>4)*4+reg
#pragma unroll
    for (int mf = 0; mf < 4; ++mf) {
        int rbase = bm + wm * 64 + mf * 16 + l4 * 4;
#pragma unroll
        for (int nf = 0; nf < 2; ++nf) {
            int col = bn + wn * 32 + nf * 16 + l15;
            if (col >= NCOL) continue;
#pragma unroll
            for (int r = 0; r < 4; ++r) {
                int row = rbase + r;
                if (row < M) {
                    float v = acc[mf][nf][r];
                    if (EPI) {
                        v += bias[col];
                        v = v > 0.f ? v : (expf(v) - 1.f);
                    }
                    if (OUT16) ((_Float16*)Cout)[(size_t)row * ldC + col] = (_Float16)v;
                    else       ((float*)Cout)[(size_t)row * ldC + col] = v;
                }
            }
        }
    }
    if (ELER) {
        const int head = blockIdx.x;           // 128-col tile == one head
        float alv[2], arv[2];
#pragma unroll
        for (int nf = 0; nf < 2; ++nf) {
            int cl = wn * 32 + nf * 16 + l15;  // col within head (0..127)
            alv[nf] = attl[head * OUTF + cl];
            arv[nf] = attr[head * OUTF + cl];
        }
        float pel[4][4], perr[4][4];
#pragma unroll
        for (int mf = 0; mf < 4; ++mf)
#pragma unroll
            for (int r = 0; r < 4; ++r) {
                float se = 0.f, sr = 0.f;
#pragma unroll
                for (int nf = 0; nf < 2; ++nf) {
                    se = fmaf(acc[mf][nf][r], alv[nf], se);
                    sr = fmaf(acc[mf][nf][r], arv[nf], sr);
                }
                pel[mf][r] = se; perr[mf][r] = sr;
            }
        // reduce across the 16-lane column group
#pragma unroll
        for (int off = 1; off < 16; off <<= 1)
#pragma unroll
            for (int mf = 0; mf < 4; ++mf)
#pragma unroll
                for (int r = 0; r < 4; ++r) {
                    pel[mf][r]  += __shfl_xor(pel[mf][r],  off);
                    perr[mf][r] += __shfl_xor(perr[mf][r], off);
                }
        __syncthreads();
        float* red = (float*)lds;              // [128][4] el, then [128][4] er
        if (l15 == 0) {
#pragma unroll
            for (int mf = 0; mf < 4; ++mf)
#pragma unroll
                for (int r = 0; r < 4; ++r) {
                    int rl = wm * 64 + mf * 16 + l4 * 4 + r;
                    red[rl * 4 + wn]       = pel[mf][r];
                    red[512 + rl * 4 + wn] = perr[mf][r];
                }
        }
        __syncthreads();
        if (tid < 128) {
            int row = bm + tid;
            if (row < M) {
                float es = red[tid * 4] + red[tid * 4 + 1] + red[tid * 4 + 2] + red[tid * 4 + 3];
                float rs = red[512 + tid * 4] + red[512 + tid * 4 + 1]
                         + red[512 + tid * 4 + 2] + red[512 + tid * 4 + 3];
                elp[row * HEADS + head] = es;
                erp[row * HEADS + head] = rs;
            }
        }
    }
}

// --------------------------- CSR build -------------------------------------
__global__ void hist_kernel(const int* __restrict__ dst, int* __restrict__ deg, int E)
{
    int e = blockIdx.x * 256 + threadIdx.x;
    if (e < E) atomicAdd(&deg[dst[e]], 1);
}

__global__ __launch_bounds__(256) void scan1_kernel(const int* __restrict__ deg,
    int* __restrict__ offs, int* __restrict__ bsum, int N)
{
    __shared__ int buf[256];
    int tid = threadIdx.x;
    int i = blockIdx.x * 256 + tid;
    int v = (i < N) ? deg[i] : 0;
    buf[tid] = v;
    __syncthreads();
#pragma unroll
    for (int off = 1; off < 256; off <<= 1) {
        int t = (tid >= off) ? buf[tid - off] : 0;
        __syncthreads();
        buf[tid] += t;
        __syncthreads();
    }
    if (i < N) offs[i] = buf[tid] - v;
    if (tid == 255) bsum[blockIdx.x] = buf[255];
}

__global__ void scan2_kernel(int* __restrict__ bsum, int nb)
{
    if (threadIdx.x == 0) {
        int acc = 0;
        for (int b = 0; b < nb; ++b) { int t = bsum[b]; bsum[b] = acc; acc += t; }
        bsum[nb] = acc;
    }
}

__global__ void scan3_kernel(int* __restrict__ offs, const int* __restrict__ bsum,
                             int N, int nb)
{
    int i = blockIdx.x * 256 + threadIdx.x;
    if (i < N) offs[i] += bsum[blockIdx.x];
    if (i == 0) offs[N] = bsum[nb];
}

// fill: write src-id directly into the node's slot (psrc = src[csr[...]])
__global__ void fill_kernel(const int* __restrict__ srcv, const int* __restrict__ dstv,
    const int* __restrict__ offs, int* __restrict__ cursor,
    int* __restrict__ psrc, int E)
{
    int e = blockIdx.x * 256 + threadIdx.x;
    if (e < E) {
        int d = dstv[e];
        int p = atomicAdd(&cursor[d], 1);
        psrc[offs[d] + p] = srcv[e];
    }
}

// ------ aggregation v4: 1 wave per node, fused edge weights ----------------
// staging computes w = exp(leakyrelu(el[s] + er[n])) in-block (er uniform).
__global__ __launch_bounds__(64) void aggregate_kernel(const _Float16* __restrict__ h,
    const int* __restrict__ offs, const int* __restrict__ psrc,
    const float* __restrict__ el, const float* __restrict__ er,
    const float* __restrict__ bias, _Float16* __restrict__ xo, int N)
{
    __shared__ int ssm[64];
    __shared__ float wsm[4][64];
    int n = blockIdx.x;
    int lane = threadIdx.x;
    int c = lane * 8;
    int head = lane >> 4;   // 8 channels per lane -> head = c/128
    float4 erv = *(const float4*)&er[n * HEADS];
    float acc[8];
#pragma unroll
    for (int k = 0; k < 8; ++k) acc[k] = 0.f;
    float ws = 0.f;
    int beg = offs[n], end = offs[n + 1];
    for (int base = beg; base < end; base += 64) {
        int cnt = min(64, end - base);
        if (lane < cnt) {
            int s = psrc[base + lane];
            float4 lv = *(const float4*)&el[s * HEADS];
            float x;
            x = lv.x + erv.x; x = x > 0.f ? x : 0.2f * x; wsm[0][lane] = expf(x);
            x = lv.y + erv.y; x = x > 0.f ? x : 0.2f * x; wsm[1][lane] = expf(x);
            x = lv.z + erv.z; x = x > 0.f ? x : 0.2f * x; wsm[2][lane] = expf(x);
            x = lv.w + erv.w; x = x > 0.f ? x : 0.2f * x; wsm[3][lane] = expf(x);
            ssm[lane] = s;
        }
        __syncthreads();
        int j = 0;
        for (; j + 4 <= cnt; j += 4) {
            int s0 = ssm[j], s1 = ssm[j + 1], s2 = ssm[j + 2], s3 = ssm[j + 3];
            float w0 = wsm[head][j],     w1 = wsm[head][j + 1];
            float w2 = wsm[head][j + 2], w3 = wsm[head][j + 3];
            f16x8_t v0 = *(const f16x8_t*)&h[(size_t)s0 * HID + c];
            f16x8_t v1 = *(const f16x8_t*)&h[(size_t)s1 * HID + c];
            f16x8_t v2 = *(const f16x8_t*)&h[(size_t)s2 * HID + c];
            f16x8_t v3 = *(const f16x8_t*)&h[(size_t)s3 * HID + c];
#pragma unroll
            for (int k = 0; k < 8; ++k) {
                acc[k] = fmaf(w0, (float)v0[k], acc[k]);
                acc[k] = fmaf(w1, (float)v1[k], acc[k]);
                acc[k] = fmaf(w2, (float)v2[k], acc[k]);
                acc[k] = fmaf(w3, (float)v3[k], acc[k]);
            }
            ws += w0 + w1 + w2 + w3;
        }
        for (; j < cnt; ++j) {
            int s0 = ssm[j];
            float w0 = wsm[head][j];
            f16x8_t v0 = *(const f16x8_t*)&h[(size_t)s0 * HID + c];
#pragma unroll
            for (int k = 0; k < 8; ++k) acc[k] = fmaf(w0, (float)v0[k], acc[k]);
            ws += w0;
        }
        __syncthreads();
    }
    float inv = 1.f / ws;
    float4 b0 = *(const float4*)&bias[c];
    float4 b1 = *(const float4*)&bias[c + 4];
    float bb[8] = {b0.x, b0.y, b0.z, b0.w, b1.x, b1.y, b1.z, b1.w};
    f16x8_t ov;
#pragma unroll
    for (int k = 0; k < 8; ++k) {
        float r = acc[k] * inv + bb[k];
        r = r > 0.f ? r : (expf(r) - 1.f);
        ov[k] = (_Float16)r;
    }
    *(f16x8_t*)&xo[(size_t)n * HID + c] = ov;
}

// ---------------------------------------------------------------------------
extern "C" void kernel_launch(void* const* d_in, const int* in_sizes, int n_in,
                              void* d_out, int out_size, void* d_ws, size_t ws_size,
                              hipStream_t stream)
{
    const float* feature = (const float*)d_in[0];
    const float* W1  = (const float*)d_in[1];
    const float* al1 = (const float*)d_in[2];
    const float* ar1 = (const float*)d_in[3];
    const float* b1  = (const float*)d_in[4];
    const float* W2  = (const float*)d_in[5];
    const float* al2 = (const float*)d_in[6];
    const float* ar2 = (const float*)d_in[7];
    const float* b2  = (const float*)d_in[8];
    const float* Wfc = (const float*)d_in[9];
    const float* bfc = (const float*)d_in[10];
    const int* src = (const int*)d_in[11];
    const int* dst = (const int*)d_in[12];
    const int N = in_sizes[0] / 1280;
    const int E = in_sizes[11];
    const int nb = (N + 255) / 256;
    float* out = (float*)d_out;

    char* ws = (char*)d_ws;
    size_t off = 0;
    auto alloc = [&](size_t bytes) {
        void* p = ws + off;
        off += (bytes + 255) & ~(size_t)255;
        return p;
    };
    int* deg    = (int*)alloc((size_t)N * 4);
    int* cursor = (int*)alloc((size_t)N * 4);
    int* offs   = (int*)alloc((size_t)(N + 1) * 4);
    int* bsum   = (int*)alloc((size_t)(nb + 1) * 4);
    float* el   = (float*)alloc((size_t)N * HEADS * 4);
    float* er   = (float*)alloc((size_t)N * HEADS * 4);
    int* psrc   = (int*)alloc((size_t)E * 4);
    _Float16* featf = (_Float16*)alloc((size_t)N * 1280 * 2);
    _Float16* hbuf  = (_Float16*)alloc((size_t)N * HID * 2);
    _Float16* xh    = (_Float16*)alloc((size_t)N * HID * 2);
    _Float16* W1t   = (_Float16*)alloc((size_t)HID * 1280 * 2);
    _Float16* W2t   = (_Float16*)alloc((size_t)HID * HID * 2);
    _Float16* Wft   = (_Float16*)alloc((size_t)64 * HID * 2);

    // CSR build (psrc written directly)
    hipMemsetAsync(deg, 0, (size_t)N * 4, stream);
    hipMemsetAsync(cursor, 0, (size_t)N * 4, stream);
    hist_kernel<<<(E + 255) / 256, 256, 0, stream>>>(dst, deg, E);
    scan1_kernel<<<nb, 256, 0, stream>>>(deg, offs, bsum, N);
    scan2_kernel<<<1, 64, 0, stream>>>(bsum, nb);
    scan3_kernel<<<nb, 256, 0, stream>>>(offs, bsum, N, nb);
    fill_kernel<<<(E + 255) / 256, 256, 0, stream>>>(src, dst, offs, cursor, psrc, E);

    // feature -> fp16 (once), W prep (fp16, transposed)
    conv16_kernel<<<2048, 256, 0, stream>>>(feature, featf, N * 1280 / 4);
    prep_w<<<dim3(1280 / 32, HID / 32), 256, 0, stream>>>(W1, W1t, 1280, HID);
    prep_w<<<dim3(HID / 32, HID / 32), 256, 0, stream>>>(W2, W2t, HID, HID);
    prep_w<<<dim3(HID / 32, 64 / 32), 256, 0, stream>>>(Wfc, Wft, HID, 64);

    dim3 ggrid(HID / 128, (N + 127) / 128);
    dim3 fgrid(1, (N + 127) / 128);

    // ---- layer 1 (GEMM + fused el/er) ----
    gemm_f16<0, 1, 1><<<ggrid, 512, 0, stream>>>(featf, W1t, nullptr,
                                                 al1, ar1, el, er,
                                                 hbuf, N, 1280, HID, HID);
    aggregate_kernel<<<N, 64, 0, stream>>>(hbuf, offs, psrc, el, er, b1, xh, N);

    // ---- layer 2 ----
    gemm_f16<0, 1, 1><<<ggrid, 512, 0, stream>>>(xh, W2t, nullptr,
                                                 al2, ar2, el, er,
                                                 hbuf, N, HID, HID, HID);
    aggregate_kernel<<<N, 64, 0, stream>>>(hbuf, offs, psrc, el, er, b2, xh, N);

    // ---- fc: MFMA GEMM with fused bias+ELU, fp32 out ----
    gemm_f16<1, 0, 0><<<fgrid, 512, 0, stream>>>(xh, Wft, bfc,
                                                 nullptr, nullptr, nullptr, nullptr,
                                                 out, N, HID, 64, 64);
}

// Round 2
// 261.956 us; speedup vs baseline: 1.0539x; 1.0539x over previous
//
#include <hip/hip_runtime.h>
#include <hip/hip_bf16.h>
#include <math.h>

#define HID 512
#define HEADS 4
#define OUTF 128

typedef __attribute__((ext_vector_type(8))) _Float16 f16x8_t;   // 8 f16 in 4 VGPRs
typedef __attribute__((ext_vector_type(4))) _Float16 f16x4_t;
typedef __attribute__((ext_vector_type(4))) float f32x4_t;

// ---------------------------------------------------------------------------
// helpers
// ---------------------------------------------------------------------------
__device__ __forceinline__ void gl_lds16(const void* g, void* l) {
    __builtin_amdgcn_global_load_lds(
        (const __attribute__((address_space(1))) void*)g,
        (__attribute__((address_space(3))) void*)l, 16, 0, 0);
}

// stage a [128 rows][32 f16] plane into LDS with XOR-chunk swizzle
// (chunk ^= (row>>1)&3), 256 threads: 2 chunks per thread.
// LDS byte gci*16 holds row (gci>>2), logical chunk (gci&3) ^ ((row>>1)&3).
// Read side measured conflict-free (same family as prior rounds: SQ_LDS_BANK_CONFLICT=0).
__device__ __forceinline__ void stage_plane32(const _Float16* g, int strideE,
    int rbase, int rmax, char* plane, int tid)
{
#pragma unroll
    for (int j = 0; j < 2; ++j) {
        int gci = j * 256 + tid;             // 0..511
        int r = gci >> 2, c = gci & 3;
        int rg = rbase + r; if (rg > rmax) rg = rmax;
        const char* s = (const char*)(g + (size_t)rg * strideE) + ((c ^ ((r >> 1) & 3)) << 4);
        char* d = plane + (j * 256 + (tid & ~63)) * 16;   // wave-uniform base
        gl_lds16(s, d);
    }
}

// ---------------------------------------------------------------------------
// fp32 -> fp16 streaming convert
// ---------------------------------------------------------------------------
__global__ __launch_bounds__(256) void conv16_kernel(const float* __restrict__ in,
    _Float16* __restrict__ o, int nquad)
{
    int stride = gridDim.x * 256;
    for (int i = blockIdx.x * 256 + threadIdx.x; i < nquad; i += stride) {
        float4 v = *(const float4*)&in[(size_t)i * 4];
        f16x4_t ov;
        ov[0] = (_Float16)v.x; ov[1] = (_Float16)v.y;
        ov[2] = (_Float16)v.z; ov[3] = (_Float16)v.w;
        *(f16x4_t*)&o[(size_t)i * 4] = ov;
    }
}

// ---------------------------------------------------------------------------
// W prep: transpose [K][NC] fp32 -> [NC][K] fp16
// ---------------------------------------------------------------------------
__global__ __launch_bounds__(256) void prep_w(const float* __restrict__ W,
    _Float16* __restrict__ Wt, int K, int NC)
{
    __shared__ float tile[32][33];
    const int k0 = blockIdx.x * 32, n0 = blockIdx.y * 32;
    const int t = threadIdx.x;
    {
        int r = t >> 3, c4 = (t & 7) * 4;
        float4 v = *(const float4*)&W[(size_t)(k0 + r) * NC + n0 + c4];
        tile[r][c4] = v.x; tile[r][c4 + 1] = v.y;
        tile[r][c4 + 2] = v.z; tile[r][c4 + 3] = v.w;
    }
    __syncthreads();
    int n = t >> 3, kc = (t & 7) * 4;
#pragma unroll
    for (int i = 0; i < 4; ++i)
        Wt[(size_t)(n0 + n) * K + k0 + kc + i] = (_Float16)tile[kc + i][n];
}

// ---------------------------------------------------------------------------
// fp16 MFMA GEMM: C[M][NCOL] = A[M][K] @ B[K][NCOL].
// 4 waves (256 thr), tile 128x128, BK=32, wave tile 64x64 (acc 4x4 frags,
// MFMA:ds_read ratio 2:1 — m97 geometry). Double-buffered K-loop, one barrier
// per K-step, 32 KB LDS -> >=3 blocks/CU so 628-block grids fully co-resident.
// 1-D grid + bijective XCD swizzle (m204): the 4 column tiles of one row-block
// land on ONE XCD so A-panel reuse is served from that XCD's L2, not L3/HBM
// (round-1 showed staging at ~7 TB/s = L3 ceiling even cache-warm).
// EPI 1: fused bias+ELU. OUT16: fp16 C. ELER 1: emit el/er (head=col tile).
// ---------------------------------------------------------------------------
template<int EPI, int OUT16, int ELER>
__global__ __launch_bounds__(256, 3) void gemm_f16(
    const _Float16* __restrict__ Af, const _Float16* __restrict__ Bt,
    const float* __restrict__ bias,
    const float* __restrict__ attl, const float* __restrict__ attr,
    float* __restrict__ elp, float* __restrict__ erp,
    void* __restrict__ Cout, int M, int K, int NCOL, int ldC,
    int ncolT, int nwg)
{
    __shared__ char lds[32768];
    const int tid = threadIdx.x;
    const int wave = tid >> 6, lane = tid & 63;
    const int wm = wave >> 1, wn = wave & 1;      // 2 x 2 wave grid
    // bijective XCD swizzle: each XCD gets a contiguous logical chunk
    const int b = blockIdx.x;
    const int q = nwg >> 3, rr = nwg & 7;
    const int xcd = b & 7, ib = b >> 3;
    const int logical = (xcd < rr ? xcd * (q + 1) : rr * (q + 1) + (xcd - rr) * q) + ib;
    const int bm = (logical / ncolT) * 128, bcol = logical % ncolT;
    const int bn = bcol * 128;
    const int l15 = lane & 15, l4 = lane >> 4;
    const int swz = (l15 >> 1) & 3;

    f32x4_t acc[4][4];
#pragma unroll
    for (int i = 0; i < 4; ++i)
#pragma unroll
        for (int j = 0; j < 4; ++j) acc[i][j] = (f32x4_t){0.f, 0.f, 0.f, 0.f};

    const int nt = K >> 5;                         // BK = 32
    stage_plane32(Af, K, bm, M - 1, lds, tid);
    stage_plane32(Bt, K, bn, NCOL - 1, lds + 8192, tid);
    __syncthreads();

    for (int t = 0; t < nt; ++t) {
        char* AH = lds + (t & 1) * 16384;
        char* BH = AH + 8192;
        if (t + 1 < nt) {
            char* AHn = lds + ((t + 1) & 1) * 16384;
            stage_plane32(Af + (t + 1) * 32, K, bm, M - 1, AHn, tid);
            stage_plane32(Bt + (t + 1) * 32, K, bn, NCOL - 1, AHn + 8192, tid);
        }
        f16x8_t fa[4], fb[4];
#pragma unroll
        for (int mf = 0; mf < 4; ++mf) {
            int row = wm * 64 + mf * 16 + l15;
            fa[mf] = *(const f16x8_t*)(AH + row * 64 + ((l4 ^ swz) << 4));
        }
#pragma unroll
        for (int nf = 0; nf < 4; ++nf) {
            int rn = wn * 64 + nf * 16 + l15;
            fb[nf] = *(const f16x8_t*)(BH + rn * 64 + ((l4 ^ swz) << 4));
        }
#pragma unroll
        for (int mf = 0; mf < 4; ++mf)
#pragma unroll
            for (int nf = 0; nf < 4; ++nf)
                acc[mf][nf] = __builtin_amdgcn_mfma_f32_16x16x32_f16(fa[mf], fb[nf], acc[mf][nf], 0, 0, 0);
        __syncthreads();
    }
    // epilogue: C/D layout col=lane&15, row=(lane>>4)*4+reg
#pragma unroll
    for (int mf = 0; mf < 4; ++mf) {
        int rbase = bm + wm * 64 + mf * 16 + l4 * 4;
#pragma unroll
        for (int nf = 0; nf < 4; ++nf) {
            int col = bn + wn * 64 + nf * 16 + l15;
            if (col >= NCOL) continue;
#pragma unroll
            for (int r = 0; r < 4; ++r) {
                int row = rbase + r;
                if (row < M) {
                    float v = acc[mf][nf][r];
                    if (EPI) {
                        v += bias[col];
                        v = v > 0.f ? v : (expf(v) - 1.f);
                    }
                    if (OUT16) ((_Float16*)Cout)[(size_t)row * ldC + col] = (_Float16)v;
                    else       ((float*)Cout)[(size_t)row * ldC + col] = v;
                }
            }
        }
    }
    if (ELER) {
        const int head = bcol;                 // 128-col tile == one head
        float alv[4], arv[4];
#pragma unroll
        for (int nf = 0; nf < 4; ++nf) {
            int cl = wn * 64 + nf * 16 + l15;  // col within head (0..127)
            alv[nf] = attl[head * OUTF + cl];
            arv[nf] = attr[head * OUTF + cl];
        }
        float pel[4][4], perr[4][4];
#pragma unroll
        for (int mf = 0; mf < 4; ++mf)
#pragma unroll
            for (int r = 0; r < 4; ++r) {
                float se = 0.f, sr = 0.f;
#pragma unroll
                for (int nf = 0; nf < 4; ++nf) {
                    se = fmaf(acc[mf][nf][r], alv[nf], se);
                    sr = fmaf(acc[mf][nf][r], arv[nf], sr);
                }
                pel[mf][r] = se; perr[mf][r] = sr;
            }
        // reduce across the 16-lane column group
#pragma unroll
        for (int off = 1; off < 16; off <<= 1)
#pragma unroll
            for (int mf = 0; mf < 4; ++mf)
#pragma unroll
                for (int r = 0; r < 4; ++r) {
                    pel[mf][r]  += __shfl_xor(pel[mf][r],  off);
                    perr[mf][r] += __shfl_xor(perr[mf][r], off);
                }
        __syncthreads();
        float* red = (float*)lds;              // [128][2] el, then [128][2] er
        if (l15 == 0) {
#pragma unroll
            for (int mf = 0; mf < 4; ++mf)
#pragma unroll
                for (int r = 0; r < 4; ++r) {
                    int rl = wm * 64 + mf * 16 + l4 * 4 + r;
                    red[rl * 2 + wn]       = pel[mf][r];
                    red[256 + rl * 2 + wn] = perr[mf][r];
                }
        }
        __syncthreads();
        if (tid < 128) {
            int row = bm + tid;
            if (row < M) {
                float es = red[tid * 2] + red[tid * 2 + 1];
                float rs = red[256 + tid * 2] + red[256 + tid * 2 + 1];
                elp[row * HEADS + head] = es;
                erp[row * HEADS + head] = rs;
            }
        }
    }
}

// --------------------------- CSR build -------------------------------------
__global__ void hist_kernel(const int* __restrict__ dst, int* __restrict__ deg, int E)
{
    int e = blockIdx.x * 256 + threadIdx.x;
    if (e < E) atomicAdd(&deg[dst[e]], 1);
}

__global__ __launch_bounds__(256) void scan1_kernel(const int* __restrict__ deg,
    int* __restrict__ offs, int* __restrict__ bsum, int N)
{
    __shared__ int buf[256];
    int tid = threadIdx.x;
    int i = blockIdx.x * 256 + tid;
    int v = (i < N) ? deg[i] : 0;
    buf[tid] = v;
    __syncthreads();
#pragma unroll
    for (int off = 1; off < 256; off <<= 1) {
        int t = (tid >= off) ? buf[tid - off] : 0;
        __syncthreads();
        buf[tid] += t;
        __syncthreads();
    }
    if (i < N) offs[i] = buf[tid] - v;
    if (tid == 255) bsum[blockIdx.x] = buf[255];
}

__global__ void scan2_kernel(int* __restrict__ bsum, int nb)
{
    if (threadIdx.x == 0) {
        int acc = 0;
        for (int b = 0; b < nb; ++b) { int t = bsum[b]; bsum[b] = acc; acc += t; }
        bsum[nb] = acc;
    }
}

__global__ void scan3_kernel(int* __restrict__ offs, const int* __restrict__ bsum,
                             int N, int nb)
{
    int i = blockIdx.x * 256 + threadIdx.x;
    if (i < N) offs[i] += bsum[blockIdx.x];
    if (i == 0) offs[N] = bsum[nb];
}

// fill: write src-id directly into the node's slot (psrc = src[csr[...]])
__global__ void fill_kernel(const int* __restrict__ srcv, const int* __restrict__ dstv,
    const int* __restrict__ offs, int* __restrict__ cursor,
    int* __restrict__ psrc, int E)
{
    int e = blockIdx.x * 256 + threadIdx.x;
    if (e < E) {
        int d = dstv[e];
        int p = atomicAdd(&cursor[d], 1);
        psrc[offs[d] + p] = srcv[e];
    }
}

// ------ aggregation v4: 1 wave per node, fused edge weights ----------------
// staging computes w = exp(leakyrelu(el[s] + er[n])) in-block (er uniform).
__global__ __launch_bounds__(64) void aggregate_kernel(const _Float16* __restrict__ h,
    const int* __restrict__ offs, const int* __restrict__ psrc,
    const float* __restrict__ el, const float* __restrict__ er,
    const float* __restrict__ bias, _Float16* __restrict__ xo, int N)
{
    __shared__ int ssm[64];
    __shared__ float wsm[4][64];
    int n = blockIdx.x;
    int lane = threadIdx.x;
    int c = lane * 8;
    int head = lane >> 4;   // 8 channels per lane -> head = c/128
    float4 erv = *(const float4*)&er[n * HEADS];
    float acc[8];
#pragma unroll
    for (int k = 0; k < 8; ++k) acc[k] = 0.f;
    float ws = 0.f;
    int beg = offs[n], end = offs[n + 1];
    for (int base = beg; base < end; base += 64) {
        int cnt = min(64, end - base);
        if (lane < cnt) {
            int s = psrc[base + lane];
            float4 lv = *(const float4*)&el[s * HEADS];
            float x;
            x = lv.x + erv.x; x = x > 0.f ? x : 0.2f * x; wsm[0][lane] = expf(x);
            x = lv.y + erv.y; x = x > 0.f ? x : 0.2f * x; wsm[1][lane] = expf(x);
            x = lv.z + erv.z; x = x > 0.f ? x : 0.2f * x; wsm[2][lane] = expf(x);
            x = lv.w + erv.w; x = x > 0.f ? x : 0.2f * x; wsm[3][lane] = expf(x);
            ssm[lane] = s;
        }
        __syncthreads();
        int j = 0;
        for (; j + 4 <= cnt; j += 4) {
            int s0 = ssm[j], s1 = ssm[j + 1], s2 = ssm[j + 2], s3 = ssm[j + 3];
            float w0 = wsm[head][j],     w1 = wsm[head][j + 1];
            float w2 = wsm[head][j + 2], w3 = wsm[head][j + 3];
            f16x8_t v0 = *(const f16x8_t*)&h[(size_t)s0 * HID + c];
            f16x8_t v1 = *(const f16x8_t*)&h[(size_t)s1 * HID + c];
            f16x8_t v2 = *(const f16x8_t*)&h[(size_t)s2 * HID + c];
            f16x8_t v3 = *(const f16x8_t*)&h[(size_t)s3 * HID + c];
#pragma unroll
            for (int k = 0; k < 8; ++k) {
                acc[k] = fmaf(w0, (float)v0[k], acc[k]);
                acc[k] = fmaf(w1, (float)v1[k], acc[k]);
                acc[k] = fmaf(w2, (float)v2[k], acc[k]);
                acc[k] = fmaf(w3, (float)v3[k], acc[k]);
            }
            ws += w0 + w1 + w2 + w3;
        }
        for (; j < cnt; ++j) {
            int s0 = ssm[j];
            float w0 = wsm[head][j];
            f16x8_t v0 = *(const f16x8_t*)&h[(size_t)s0 * HID + c];
#pragma unroll
            for (int k = 0; k < 8; ++k) acc[k] = fmaf(w0, (float)v0[k], acc[k]);
            ws += w0;
        }
        __syncthreads();
    }
    float inv = 1.f / ws;
    float4 b0 = *(const float4*)&bias[c];
    float4 b1 = *(const float4*)&bias[c + 4];
    float bb[8] = {b0.x, b0.y, b0.z, b0.w, b1.x, b1.y, b1.z, b1.w};
    f16x8_t ov;
#pragma unroll
    for (int k = 0; k < 8; ++k) {
        float r = acc[k] * inv + bb[k];
        r = r > 0.f ? r : (expf(r) - 1.f);
        ov[k] = (_Float16)r;
    }
    *(f16x8_t*)&xo[(size_t)n * HID + c] = ov;
}

// ---------------------------------------------------------------------------
extern "C" void kernel_launch(void* const* d_in, const int* in_sizes, int n_in,
                              void* d_out, int out_size, void* d_ws, size_t ws_size,
                              hipStream_t stream)
{
    const float* feature = (const float*)d_in[0];
    const float* W1  = (const float*)d_in[1];
    const float* al1 = (const float*)d_in[2];
    const float* ar1 = (const float*)d_in[3];
    const float* b1  = (const float*)d_in[4];
    const float* W2  = (const float*)d_in[5];
    const float* al2 = (const float*)d_in[6];
    const float* ar2 = (const float*)d_in[7];
    const float* b2  = (const float*)d_in[8];
    const float* Wfc = (const float*)d_in[9];
    const float* bfc = (const float*)d_in[10];
    const int* src = (const int*)d_in[11];
    const int* dst = (const int*)d_in[12];
    const int N = in_sizes[0] / 1280;
    const int E = in_sizes[11];
    const int nb = (N + 255) / 256;
    float* out = (float*)d_out;

    char* ws = (char*)d_ws;
    size_t off = 0;
    auto alloc = [&](size_t bytes) {
        void* p = ws + off;
        off += (bytes + 255) & ~(size_t)255;
        return p;
    };
    int* deg    = (int*)alloc((size_t)N * 4);
    int* cursor = (int*)alloc((size_t)N * 4);
    int* offs   = (int*)alloc((size_t)(N + 1) * 4);
    int* bsum   = (int*)alloc((size_t)(nb + 1) * 4);
    float* el   = (float*)alloc((size_t)N * HEADS * 4);
    float* er   = (float*)alloc((size_t)N * HEADS * 4);
    int* psrc   = (int*)alloc((size_t)E * 4);
    _Float16* featf = (_Float16*)alloc((size_t)N * 1280 * 2);
    _Float16* hbuf  = (_Float16*)alloc((size_t)N * HID * 2);
    _Float16* xh    = (_Float16*)alloc((size_t)N * HID * 2);
    _Float16* W1t   = (_Float16*)alloc((size_t)HID * 1280 * 2);
    _Float16* W2t   = (_Float16*)alloc((size_t)HID * HID * 2);
    _Float16* Wft   = (_Float16*)alloc((size_t)64 * HID * 2);

    // CSR build (psrc written directly)
    hipMemsetAsync(deg, 0, (size_t)N * 4, stream);
    hipMemsetAsync(cursor, 0, (size_t)N * 4, stream);
    hist_kernel<<<(E + 255) / 256, 256, 0, stream>>>(dst, deg, E);
    scan1_kernel<<<nb, 256, 0, stream>>>(deg, offs, bsum, N);
    scan2_kernel<<<1, 64, 0, stream>>>(bsum, nb);
    scan3_kernel<<<nb, 256, 0, stream>>>(offs, bsum, N, nb);
    fill_kernel<<<(E + 255) / 256, 256, 0, stream>>>(src, dst, offs, cursor, psrc, E);

    // feature -> fp16 (once), W prep (fp16, transposed)
    conv16_kernel<<<2048, 256, 0, stream>>>(feature, featf, N * 1280 / 4);
    prep_w<<<dim3(1280 / 32, HID / 32), 256, 0, stream>>>(W1, W1t, 1280, HID);
    prep_w<<<dim3(HID / 32, HID / 32), 256, 0, stream>>>(W2, W2t, HID, HID);
    prep_w<<<dim3(HID / 32, 64 / 32), 256, 0, stream>>>(Wfc, Wft, HID, 64);

    const int nrowT = (N + 127) / 128;
    const int nwgG = nrowT * (HID / 128);   // 4 col tiles
    const int nwgF = nrowT;                 // 1 col tile (NCOL=64)

    // ---- layer 1 (GEMM + fused el/er) ----
    gemm_f16<0, 1, 1><<<nwgG, 256, 0, stream>>>(featf, W1t, nullptr,
                                                al1, ar1, el, er,
                                                hbuf, N, 1280, HID, HID,
                                                HID / 128, nwgG);
    aggregate_kernel<<<N, 64, 0, stream>>>(hbuf, offs, psrc, el, er, b1, xh, N);

    // ---- layer 2 ----
    gemm_f16<0, 1, 1><<<nwgG, 256, 0, stream>>>(xh, W2t, nullptr,
                                                al2, ar2, el, er,
                                                hbuf, N, HID, HID, HID,
                                                HID / 128, nwgG);
    aggregate_kernel<<<N, 64, 0, stream>>>(hbuf, offs, psrc, el, er, b2, xh, N);

    // ---- fc: MFMA GEMM with fused bias+ELU, fp32 out ----
    gemm_f16<1, 0, 0><<<nwgF, 256, 0, stream>>>(xh, Wft, bfc,
                                                nullptr, nullptr, nullptr, nullptr,
                                                out, N, HID, 64, 64,
                                                1, nwgF);
}

// Round 3
// 260.306 us; speedup vs baseline: 1.0606x; 1.0063x over previous
//
#include <hip/hip_runtime.h>
#include <hip/hip_bf16.h>
#include <math.h>

#define HID 512
#define HEADS 4
#define OUTF 128

typedef __attribute__((ext_vector_type(8))) _Float16 f16x8_t;   // 8 f16 in 4 VGPRs
typedef __attribute__((ext_vector_type(4))) _Float16 f16x4_t;
typedef __attribute__((ext_vector_type(4))) float f32x4_t;

// ---------------------------------------------------------------------------
// helpers
// ---------------------------------------------------------------------------
__device__ __forceinline__ void gl_lds16(const void* g, void* l) {
    __builtin_amdgcn_global_load_lds(
        (const __attribute__((address_space(1))) void*)g,
        (__attribute__((address_space(3))) void*)l, 16, 0, 0);
}

// stage a [128 rows][32 f16] plane into LDS with XOR-chunk swizzle
// (chunk ^= (row>>1)&3), 256 threads: 2 chunks per thread.
// LDS byte gci*16 holds row (gci>>2), logical chunk (gci&3) ^ ((row>>1)&3).
// Read side measured conflict-free (SQ_LDS_BANK_CONFLICT=0 across rounds).
__device__ __forceinline__ void stage_plane32(const _Float16* g, int strideE,
    int rbase, int rmax, char* plane, int tid)
{
#pragma unroll
    for (int j = 0; j < 2; ++j) {
        int gci = j * 256 + tid;             // 0..511
        int r = gci >> 2, c = gci & 3;
        int rg = rbase + r; if (rg > rmax) rg = rmax;
        const char* s = (const char*)(g + (size_t)rg * strideE) + ((c ^ ((r >> 1) & 3)) << 4);
        char* d = plane + (j * 256 + (tid & ~63)) * 16;   // wave-uniform base
        gl_lds16(s, d);
    }
}

// ---------------------------------------------------------------------------
// fp32 -> fp16 streaming convert
// ---------------------------------------------------------------------------
__global__ __launch_bounds__(256) void conv16_kernel(const float* __restrict__ in,
    _Float16* __restrict__ o, int nquad)
{
    int stride = gridDim.x * 256;
    for (int i = blockIdx.x * 256 + threadIdx.x; i < nquad; i += stride) {
        float4 v = *(const float4*)&in[(size_t)i * 4];
        f16x4_t ov;
        ov[0] = (_Float16)v.x; ov[1] = (_Float16)v.y;
        ov[2] = (_Float16)v.z; ov[3] = (_Float16)v.w;
        *(f16x4_t*)&o[(size_t)i * 4] = ov;
    }
}

// ---------------------------------------------------------------------------
// W prep: transpose [K][NC] fp32 -> [NC][K] fp16
// ---------------------------------------------------------------------------
__global__ __launch_bounds__(256) void prep_w(const float* __restrict__ W,
    _Float16* __restrict__ Wt, int K, int NC)
{
    __shared__ float tile[32][33];
    const int k0 = blockIdx.x * 32, n0 = blockIdx.y * 32;
    const int t = threadIdx.x;
    {
        int r = t >> 3, c4 = (t & 7) * 4;
        float4 v = *(const float4*)&W[(size_t)(k0 + r) * NC + n0 + c4];
        tile[r][c4] = v.x; tile[r][c4 + 1] = v.y;
        tile[r][c4 + 2] = v.z; tile[r][c4 + 3] = v.w;
    }
    __syncthreads();
    int n = t >> 3, kc = (t & 7) * 4;
#pragma unroll
    for (int i = 0; i < 4; ++i)
        Wt[(size_t)(n0 + n) * K + k0 + kc + i] = (_Float16)tile[kc + i][n];
}

// ---------------------------------------------------------------------------
// fp16 MFMA GEMM: C[M][NCOL] = A[M][K] @ B[K][NCOL].
// 4 waves (256 thr), tile 128x128, BK=32, wave tile 64x64 (acc 4x4 frags).
// Double-buffered K-loop, one barrier per K-step, 32 KB LDS -> 3 blocks/CU.
// 1-D grid + bijective XCD swizzle (m204): 4 column tiles of one row-block on
// ONE XCD so A-panel reuse is L2-served.
// EPI 1: fused bias+ELU. OUT16: fp16 C. ELER 1: emit el/er (head=col tile).
// ---------------------------------------------------------------------------
template<int EPI, int OUT16, int ELER>
__global__ __launch_bounds__(256, 3) void gemm_f16(
    const _Float16* __restrict__ Af, const _Float16* __restrict__ Bt,
    const float* __restrict__ bias,
    const float* __restrict__ attl, const float* __restrict__ attr,
    float* __restrict__ elp, float* __restrict__ erp,
    void* __restrict__ Cout, int M, int K, int NCOL, int ldC,
    int ncolT, int nwg)
{
    __shared__ char lds[32768];
    const int tid = threadIdx.x;
    const int wave = tid >> 6, lane = tid & 63;
    const int wm = wave >> 1, wn = wave & 1;      // 2 x 2 wave grid
    // bijective XCD swizzle: each XCD gets a contiguous logical chunk
    const int b = blockIdx.x;
    const int q = nwg >> 3, rr = nwg & 7;
    const int xcd = b & 7, ib = b >> 3;
    const int logical = (xcd < rr ? xcd * (q + 1) : rr * (q + 1) + (xcd - rr) * q) + ib;
    const int bm = (logical / ncolT) * 128, bcol = logical % ncolT;
    const int bn = bcol * 128;
    const int l15 = lane & 15, l4 = lane >> 4;
    const int swz = (l15 >> 1) & 3;

    f32x4_t acc[4][4];
#pragma unroll
    for (int i = 0; i < 4; ++i)
#pragma unroll
        for (int j = 0; j < 4; ++j) acc[i][j] = (f32x4_t){0.f, 0.f, 0.f, 0.f};

    const int nt = K >> 5;                         // BK = 32
    stage_plane32(Af, K, bm, M - 1, lds, tid);
    stage_plane32(Bt, K, bn, NCOL - 1, lds + 8192, tid);
    __syncthreads();

    for (int t = 0; t < nt; ++t) {
        char* AH = lds + (t & 1) * 16384;
        char* BH = AH + 8192;
        if (t + 1 < nt) {
            char* AHn = lds + ((t + 1) & 1) * 16384;
            stage_plane32(Af + (t + 1) * 32, K, bm, M - 1, AHn, tid);
            stage_plane32(Bt + (t + 1) * 32, K, bn, NCOL - 1, AHn + 8192, tid);
        }
        f16x8_t fa[4], fb[4];
#pragma unroll
        for (int mf = 0; mf < 4; ++mf) {
            int row = wm * 64 + mf * 16 + l15;
            fa[mf] = *(const f16x8_t*)(AH + row * 64 + ((l4 ^ swz) << 4));
        }
#pragma unroll
        for (int nf = 0; nf < 4; ++nf) {
            int rn = wn * 64 + nf * 16 + l15;
            fb[nf] = *(const f16x8_t*)(BH + rn * 64 + ((l4 ^ swz) << 4));
        }
#pragma unroll
        for (int mf = 0; mf < 4; ++mf)
#pragma unroll
            for (int nf = 0; nf < 4; ++nf)
                acc[mf][nf] = __builtin_amdgcn_mfma_f32_16x16x32_f16(fa[mf], fb[nf], acc[mf][nf], 0, 0, 0);
        __syncthreads();
    }
    // epilogue: C/D layout col=lane&15, row=(lane>>4)*4+reg
#pragma unroll
    for (int mf = 0; mf < 4; ++mf) {
        int rbase = bm + wm * 64 + mf * 16 + l4 * 4;
#pragma unroll
        for (int nf = 0; nf < 4; ++nf) {
            int col = bn + wn * 64 + nf * 16 + l15;
            if (col >= NCOL) continue;
#pragma unroll
            for (int r = 0; r < 4; ++r) {
                int row = rbase + r;
                if (row < M) {
                    float v = acc[mf][nf][r];
                    if (EPI) {
                        v += bias[col];
                        v = v > 0.f ? v : (expf(v) - 1.f);
                    }
                    if (OUT16) ((_Float16*)Cout)[(size_t)row * ldC + col] = (_Float16)v;
                    else       ((float*)Cout)[(size_t)row * ldC + col] = v;
                }
            }
        }
    }
    if (ELER) {
        const int head = bcol;                 // 128-col tile == one head
        float alv[4], arv[4];
#pragma unroll
        for (int nf = 0; nf < 4; ++nf) {
            int cl = wn * 64 + nf * 16 + l15;  // col within head (0..127)
            alv[nf] = attl[head * OUTF + cl];
            arv[nf] = attr[head * OUTF + cl];
        }
        float pel[4][4], perr[4][4];
#pragma unroll
        for (int mf = 0; mf < 4; ++mf)
#pragma unroll
            for (int r = 0; r < 4; ++r) {
                float se = 0.f, sr = 0.f;
#pragma unroll
                for (int nf = 0; nf < 4; ++nf) {
                    se = fmaf(acc[mf][nf][r], alv[nf], se);
                    sr = fmaf(acc[mf][nf][r], arv[nf], sr);
                }
                pel[mf][r] = se; perr[mf][r] = sr;
            }
        // reduce across the 16-lane column group
#pragma unroll
        for (int off = 1; off < 16; off <<= 1)
#pragma unroll
            for (int mf = 0; mf < 4; ++mf)
#pragma unroll
                for (int r = 0; r < 4; ++r) {
                    pel[mf][r]  += __shfl_xor(pel[mf][r],  off);
                    perr[mf][r] += __shfl_xor(perr[mf][r], off);
                }
        __syncthreads();
        float* red = (float*)lds;              // [128][2] el, then [128][2] er
        if (l15 == 0) {
#pragma unroll
            for (int mf = 0; mf < 4; ++mf)
#pragma unroll
                for (int r = 0; r < 4; ++r) {
                    int rl = wm * 64 + mf * 16 + l4 * 4 + r;
                    red[rl * 2 + wn]       = pel[mf][r];
                    red[256 + rl * 2 + wn] = perr[mf][r];
                }
        }
        __syncthreads();
        if (tid < 128) {
            int row = bm + tid;
            if (row < M) {
                float es = red[tid * 2] + red[tid * 2 + 1];
                float rs = red[256 + tid * 2] + red[256 + tid * 2 + 1];
                elp[row * HEADS + head] = es;
                erp[row * HEADS + head] = rs;
            }
        }
    }
}

// --------------------------- CSR build -------------------------------------
__global__ void hist_kernel(const int* __restrict__ dst, int* __restrict__ deg, int E)
{
    int e = blockIdx.x * 256 + threadIdx.x;
    if (e < E) atomicAdd(&deg[dst[e]], 1);
}

__global__ __launch_bounds__(256) void scan1_kernel(const int* __restrict__ deg,
    int* __restrict__ offs, int* __restrict__ bsum, int N)
{
    __shared__ int buf[256];
    int tid = threadIdx.x;
    int i = blockIdx.x * 256 + tid;
    int v = (i < N) ? deg[i] : 0;
    buf[tid] = v;
    __syncthreads();
#pragma unroll
    for (int off = 1; off < 256; off <<= 1) {
        int t = (tid >= off) ? buf[tid - off] : 0;
        __syncthreads();
        buf[tid] += t;
        __syncthreads();
    }
    if (i < N) offs[i] = buf[tid] - v;
    if (tid == 255) bsum[blockIdx.x] = buf[255];
}

__global__ void scan2_kernel(int* __restrict__ bsum, int nb)
{
    if (threadIdx.x == 0) {
        int acc = 0;
        for (int b = 0; b < nb; ++b) { int t = bsum[b]; bsum[b] = acc; acc += t; }
        bsum[nb] = acc;
    }
}

__global__ void scan3_kernel(int* __restrict__ offs, const int* __restrict__ bsum,
                             int N, int nb)
{
    int i = blockIdx.x * 256 + threadIdx.x;
    if (i < N) offs[i] += bsum[blockIdx.x];
    if (i == 0) offs[N] = bsum[nb];
}

// fill: write src-id directly into the node's slot (psrc = src[csr[...]])
__global__ void fill_kernel(const int* __restrict__ srcv, const int* __restrict__ dstv,
    const int* __restrict__ offs, int* __restrict__ cursor,
    int* __restrict__ psrc, int E)
{
    int e = blockIdx.x * 256 + threadIdx.x;
    if (e < E) {
        int d = dstv[e];
        int p = atomicAdd(&cursor[d], 1);
        psrc[offs[d] + p] = srcv[e];
    }
}

// ------ aggregation v5: barrier-free shuffle-broadcast, 4 nodes/block ------
// One wave per node (4 waves / 256-thr block -> 8 blocks/CU = 32 waves/CU,
// 2x the old 1-wave-block occupancy). Chunk = 32 edges, staged entirely in
// registers: lane L stages edge (L&31) for head-pair (L>>5) -- one float2 el
// gather + 2 exp. Weights and source ids broadcast via __shfl (wave lockstep
// => no LDS, no __syncthreads). h-row loads issue as soon as psrc returns,
// overlapping the el/exp chain. P(deg>32) ~ 0 (Poisson lambda=16) so almost
// every node is a single stage chain.
__global__ __launch_bounds__(256) void aggregate_kernel(const _Float16* __restrict__ h,
    const int* __restrict__ offs, const int* __restrict__ psrc,
    const float* __restrict__ el, const float* __restrict__ er,
    const float* __restrict__ bias, _Float16* __restrict__ xo, int N)
{
    const int n = blockIdx.x * 4 + (threadIdx.x >> 6);
    if (n >= N) return;
    const int lane = threadIdx.x & 63;
    const int c = lane * 8;
    const int head = lane >> 4;           // reader head (0..3)
    const int hp = lane >> 5;             // staged head-pair (0:h01, 1:h23)
    const int e31 = lane & 31;
    const int sbase = (head >> 1) << 5;   // source-lane base for my head-pair
    const int hsel = head & 1;

    const float2 er2 = *(const float2*)&er[n * HEADS + hp * 2];

    float acc[8];
#pragma unroll
    for (int k = 0; k < 8; ++k) acc[k] = 0.f;
    float ws = 0.f;

    const int beg = offs[n], end = offs[n + 1];
    for (int base = beg; base < end; base += 32) {
        const int cnt = min(32, end - base);
        int idx = base + e31;
        if (e31 >= cnt) idx = beg;        // safe dummy (deg >= 1: self loop)
        const int s = psrc[idx];
        const float2 lv = *(const float2*)&el[s * HEADS + hp * 2];
        float x0 = lv.x + er2.x; x0 = x0 > 0.f ? x0 : 0.2f * x0;
        float x1 = lv.y + er2.y; x1 = x1 > 0.f ? x1 : 0.2f * x1;
        const float wa = expf(x0);        // weight for head hp*2
        const float wb = expf(x1);        // weight for head hp*2+1

        int j = 0;
        for (; j + 4 <= cnt; j += 4) {
            int s0 = __shfl(s, j);     int s1 = __shfl(s, j + 1);
            int s2 = __shfl(s, j + 2); int s3 = __shfl(s, j + 3);
            float a0 = __shfl(wa, sbase + j),     b0 = __shfl(wb, sbase + j);
            float a1 = __shfl(wa, sbase + j + 1), b1 = __shfl(wb, sbase + j + 1);
            float a2 = __shfl(wa, sbase + j + 2), b2 = __shfl(wb, sbase + j + 2);
            float a3 = __shfl(wa, sbase + j + 3), b3 = __shfl(wb, sbase + j + 3);
            float w0 = hsel ? b0 : a0;
            float w1 = hsel ? b1 : a1;
            float w2 = hsel ? b2 : a2;
            float w3 = hsel ? b3 : a3;
            f16x8_t v0 = *(const f16x8_t*)&h[(size_t)s0 * HID + c];
            f16x8_t v1 = *(const f16x8_t*)&h[(size_t)s1 * HID + c];
            f16x8_t v2 = *(const f16x8_t*)&h[(size_t)s2 * HID + c];
            f16x8_t v3 = *(const f16x8_t*)&h[(size_t)s3 * HID + c];
#pragma unroll
            for (int k = 0; k < 8; ++k) {
                acc[k] = fmaf(w0, (float)v0[k], acc[k]);
                acc[k] = fmaf(w1, (float)v1[k], acc[k]);
                acc[k] = fmaf(w2, (float)v2[k], acc[k]);
                acc[k] = fmaf(w3, (float)v3[k], acc[k]);
            }
            ws += w0 + w1 + w2 + w3;
        }
        for (; j < cnt; ++j) {
            int s0 = __shfl(s, j);
            float a0 = __shfl(wa, sbase + j), b0 = __shfl(wb, sbase + j);
            float w0 = hsel ? b0 : a0;
            f16x8_t v0 = *(const f16x8_t*)&h[(size_t)s0 * HID + c];
#pragma unroll
            for (int k = 0; k < 8; ++k) acc[k] = fmaf(w0, (float)v0[k], acc[k]);
            ws += w0;
        }
    }
    float inv = 1.f / ws;
    float4 b0v = *(const float4*)&bias[c];
    float4 b1v = *(const float4*)&bias[c + 4];
    float bb[8] = {b0v.x, b0v.y, b0v.z, b0v.w, b1v.x, b1v.y, b1v.z, b1v.w};
    f16x8_t ov;
#pragma unroll
    for (int k = 0; k < 8; ++k) {
        float r = acc[k] * inv + bb[k];
        r = r > 0.f ? r : (expf(r) - 1.f);
        ov[k] = (_Float16)r;
    }
    *(f16x8_t*)&xo[(size_t)n * HID + c] = ov;
}

// ---------------------------------------------------------------------------
extern "C" void kernel_launch(void* const* d_in, const int* in_sizes, int n_in,
                              void* d_out, int out_size, void* d_ws, size_t ws_size,
                              hipStream_t stream)
{
    const float* feature = (const float*)d_in[0];
    const float* W1  = (const float*)d_in[1];
    const float* al1 = (const float*)d_in[2];
    const float* ar1 = (const float*)d_in[3];
    const float* b1  = (const float*)d_in[4];
    const float* W2  = (const float*)d_in[5];
    const float* al2 = (const float*)d_in[6];
    const float* ar2 = (const float*)d_in[7];
    const float* b2  = (const float*)d_in[8];
    const float* Wfc = (const float*)d_in[9];
    const float* bfc = (const float*)d_in[10];
    const int* src = (const int*)d_in[11];
    const int* dst = (const int*)d_in[12];
    const int N = in_sizes[0] / 1280;
    const int E = in_sizes[11];
    const int nb = (N + 255) / 256;
    float* out = (float*)d_out;

    char* ws = (char*)d_ws;
    size_t off = 0;
    auto alloc = [&](size_t bytes) {
        void* p = ws + off;
        off += (bytes + 255) & ~(size_t)255;
        return p;
    };
    int* deg    = (int*)alloc((size_t)N * 4);
    int* cursor = (int*)alloc((size_t)N * 4);
    int* offs   = (int*)alloc((size_t)(N + 1) * 4);
    int* bsum   = (int*)alloc((size_t)(nb + 1) * 4);
    float* el   = (float*)alloc((size_t)N * HEADS * 4);
    float* er   = (float*)alloc((size_t)N * HEADS * 4);
    int* psrc   = (int*)alloc((size_t)E * 4);
    _Float16* featf = (_Float16*)alloc((size_t)N * 1280 * 2);
    _Float16* hbuf  = (_Float16*)alloc((size_t)N * HID * 2);
    _Float16* xh    = (_Float16*)alloc((size_t)N * HID * 2);
    _Float16* W1t   = (_Float16*)alloc((size_t)HID * 1280 * 2);
    _Float16* W2t   = (_Float16*)alloc((size_t)HID * HID * 2);
    _Float16* Wft   = (_Float16*)alloc((size_t)64 * HID * 2);

    // CSR build (psrc written directly)
    hipMemsetAsync(deg, 0, (size_t)N * 4, stream);
    hipMemsetAsync(cursor, 0, (size_t)N * 4, stream);
    hist_kernel<<<(E + 255) / 256, 256, 0, stream>>>(dst, deg, E);
    scan1_kernel<<<nb, 256, 0, stream>>>(deg, offs, bsum, N);
    scan2_kernel<<<1, 64, 0, stream>>>(bsum, nb);
    scan3_kernel<<<nb, 256, 0, stream>>>(offs, bsum, N, nb);
    fill_kernel<<<(E + 255) / 256, 256, 0, stream>>>(src, dst, offs, cursor, psrc, E);

    // feature -> fp16 (once), W prep (fp16, transposed)
    conv16_kernel<<<2048, 256, 0, stream>>>(feature, featf, N * 1280 / 4);
    prep_w<<<dim3(1280 / 32, HID / 32), 256, 0, stream>>>(W1, W1t, 1280, HID);
    prep_w<<<dim3(HID / 32, HID / 32), 256, 0, stream>>>(W2, W2t, HID, HID);
    prep_w<<<dim3(HID / 32, 64 / 32), 256, 0, stream>>>(Wfc, Wft, HID, 64);

    const int nrowT = (N + 127) / 128;
    const int nwgG = nrowT * (HID / 128);   // 4 col tiles
    const int nwgF = nrowT;                 // 1 col tile (NCOL=64)
    const int aggB = (N + 3) / 4;

    // ---- layer 1 (GEMM + fused el/er) ----
    gemm_f16<0, 1, 1><<<nwgG, 256, 0, stream>>>(featf, W1t, nullptr,
                                                al1, ar1, el, er,
                                                hbuf, N, 1280, HID, HID,
                                                HID / 128, nwgG);
    aggregate_kernel<<<aggB, 256, 0, stream>>>(hbuf, offs, psrc, el, er, b1, xh, N);

    // ---- layer 2 ----
    gemm_f16<0, 1, 1><<<nwgG, 256, 0, stream>>>(xh, W2t, nullptr,
                                                al2, ar2, el, er,
                                                hbuf, N, HID, HID, HID,
                                                HID / 128, nwgG);
    aggregate_kernel<<<aggB, 256, 0, stream>>>(hbuf, offs, psrc, el, er, b2, xh, N);

    // ---- fc: MFMA GEMM with fused bias+ELU, fp32 out ----
    gemm_f16<1, 0, 0><<<nwgF, 256, 0, stream>>>(xh, Wft, bfc,
                                                nullptr, nullptr, nullptr, nullptr,
                                                out, N, HID, 64, 64,
                                                1, nwgF);
}

// Round 4
// 248.189 us; speedup vs baseline: 1.1123x; 1.0488x over previous
//
#include <hip/hip_runtime.h>
#include <hip/hip_bf16.h>
#include <math.h>

#define HID 512
#define HEADS 4
#define OUTF 128

typedef __attribute__((ext_vector_type(8))) _Float16 f16x8_t;   // 8 f16 in 4 VGPRs
typedef __attribute__((ext_vector_type(4))) _Float16 f16x4_t;
typedef __attribute__((ext_vector_type(4))) float f32x4_t;

// ---------------------------------------------------------------------------
// helpers
// ---------------------------------------------------------------------------
__device__ __forceinline__ void gl_lds16(const void* g, void* l) {
    __builtin_amdgcn_global_load_lds(
        (const __attribute__((address_space(1))) void*)g,
        (__attribute__((address_space(3))) void*)l, 16, 0, 0);
}

// stage a [128 rows][32 f16] plane into LDS with XOR-chunk swizzle
// (chunk ^= (row>>1)&3), 256 threads: 2 chunks per thread.
// LDS byte gci*16 holds row (gci>>2), logical chunk (gci&3) ^ ((row>>1)&3).
// Read side measured conflict-free (SQ_LDS_BANK_CONFLICT=0 across rounds).
__device__ __forceinline__ void stage_plane32(const _Float16* g, int strideE,
    int rbase, int rmax, char* plane, int tid)
{
#pragma unroll
    for (int j = 0; j < 2; ++j) {
        int gci = j * 256 + tid;             // 0..511
        int r = gci >> 2, c = gci & 3;
        int rg = rbase + r; if (rg > rmax) rg = rmax;
        const char* s = (const char*)(g + (size_t)rg * strideE) + ((c ^ ((r >> 1) & 3)) << 4);
        char* d = plane + (j * 256 + (tid & ~63)) * 16;   // wave-uniform base
        gl_lds16(s, d);
    }
}

// fp32 A staging (fused conv16): per thread 2 chunks (gci=j*256+tid) of
// 16B f16 destined for the SAME LDS image as stage_plane32, sourced from
// 32B of fp32 at row gci>>2 (clamped), chunk (gci&3)^((row>>1)&3).
// Split into issue-early load (T14) and cvt+ds_write after the MFMA block.
__device__ __forceinline__ void a32_load(const float* g, int strideE,
    int rbase, int rmax, int tid, int kbase, float4* v)
{
#pragma unroll
    for (int j = 0; j < 2; ++j) {
        int gci = j * 256 + tid;
        int r = gci >> 2, c = gci & 3;
        int rg = rbase + r; if (rg > rmax) rg = rmax;
        const float* s = g + (size_t)rg * strideE + kbase + ((c ^ ((r >> 1) & 3)) << 3);
        v[j * 2]     = *(const float4*)s;
        v[j * 2 + 1] = *(const float4*)(s + 4);
    }
}
__device__ __forceinline__ void a32_write(char* plane, int tid, const float4* v)
{
#pragma unroll
    for (int j = 0; j < 2; ++j) {
        const float4 a = v[j * 2], b = v[j * 2 + 1];
        f16x8_t o;
        o[0] = (_Float16)a.x; o[1] = (_Float16)a.y;
        o[2] = (_Float16)a.z; o[3] = (_Float16)a.w;
        o[4] = (_Float16)b.x; o[5] = (_Float16)b.y;
        o[6] = (_Float16)b.z; o[7] = (_Float16)b.w;
        *(f16x8_t*)(plane + (j * 256 + tid) * 16) = o;
    }
}

// ---------------------------------------------------------------------------
// W prep: transpose [K][NC] fp32 -> [NC][K] fp16
// ---------------------------------------------------------------------------
__global__ __launch_bounds__(256) void prep_w(const float* __restrict__ W,
    _Float16* __restrict__ Wt, int K, int NC)
{
    __shared__ float tile[32][33];
    const int k0 = blockIdx.x * 32, n0 = blockIdx.y * 32;
    const int t = threadIdx.x;
    {
        int r = t >> 3, c4 = (t & 7) * 4;
        float4 v = *(const float4*)&W[(size_t)(k0 + r) * NC + n0 + c4];
        tile[r][c4] = v.x; tile[r][c4 + 1] = v.y;
        tile[r][c4 + 2] = v.z; tile[r][c4 + 3] = v.w;
    }
    __syncthreads();
    int n = t >> 3, kc = (t & 7) * 4;
#pragma unroll
    for (int i = 0; i < 4; ++i)
        Wt[(size_t)(n0 + n) * K + k0 + kc + i] = (_Float16)tile[kc + i][n];
}

// ---------------------------------------------------------------------------
// fp16 MFMA GEMM: C[M][NCOL] = A[M][K] @ B[K][NCOL].
// 4 waves (256 thr), tile 128x128, BK=32, wave tile 64x64 (acc 4x4 frags).
// Double-buffered K-loop, one barrier per K-step, 32 KB LDS -> 3 blocks/CU.
// 1-D grid + bijective XCD swizzle (m204): 4 column tiles of one row-block on
// ONE XCD so A-panel reuse is L2-served.
// A32 1: A is fp32, reg-staged + converted to the identical f16 LDS image
// (fuses the old conv16 pass into the GEMM; saves ~150 MB of HBM).
// EPI 1: fused bias+ELU. OUT16: fp16 C. ELER 1: emit el/er (head=col tile).
// ---------------------------------------------------------------------------
template<int EPI, int OUT16, int ELER, int A32>
__global__ __launch_bounds__(256, 3) void gemm_f16(
    const void* __restrict__ Ap, const _Float16* __restrict__ Bt,
    const float* __restrict__ bias,
    const float* __restrict__ attl, const float* __restrict__ attr,
    float* __restrict__ elp, float* __restrict__ erp,
    void* __restrict__ Cout, int M, int K, int NCOL, int ldC,
    int ncolT, int nwg)
{
    __shared__ char lds[32768];
    const _Float16* Af  = (const _Float16*)Ap;
    const float*    Af32 = (const float*)Ap;
    const int tid = threadIdx.x;
    const int wave = tid >> 6, lane = tid & 63;
    const int wm = wave >> 1, wn = wave & 1;      // 2 x 2 wave grid
    // bijective XCD swizzle: each XCD gets a contiguous logical chunk
    const int b = blockIdx.x;
    const int q = nwg >> 3, rr = nwg & 7;
    const int xcd = b & 7, ib = b >> 3;
    const int logical = (xcd < rr ? xcd * (q + 1) : rr * (q + 1) + (xcd - rr) * q) + ib;
    const int bm = (logical / ncolT) * 128, bcol = logical % ncolT;
    const int bn = bcol * 128;
    const int l15 = lane & 15, l4 = lane >> 4;
    const int swz = (l15 >> 1) & 3;

    f32x4_t acc[4][4];
#pragma unroll
    for (int i = 0; i < 4; ++i)
#pragma unroll
        for (int j = 0; j < 4; ++j) acc[i][j] = (f32x4_t){0.f, 0.f, 0.f, 0.f};

    const int nt = K >> 5;                         // BK = 32
    float4 pre[4];
    if (A32) {
        a32_load(Af32, K, bm, M - 1, tid, 0, pre);
        a32_write(lds, tid, pre);
    } else {
        stage_plane32(Af, K, bm, M - 1, lds, tid);
    }
    stage_plane32(Bt, K, bn, NCOL - 1, lds + 8192, tid);
    __syncthreads();

    for (int t = 0; t < nt; ++t) {
        char* AH = lds + (t & 1) * 16384;
        char* BH = AH + 8192;
        char* AHn = lds + ((t + 1) & 1) * 16384;
        if (t + 1 < nt) {
            if (A32) a32_load(Af32, K, bm, M - 1, tid, (t + 1) * 32, pre);
            else     stage_plane32(Af + (t + 1) * 32, K, bm, M - 1, AHn, tid);
            stage_plane32(Bt + (t + 1) * 32, K, bn, NCOL - 1, AHn + 8192, tid);
        }
        f16x8_t fa[4], fb[4];
#pragma unroll
        for (int mf = 0; mf < 4; ++mf) {
            int row = wm * 64 + mf * 16 + l15;
            fa[mf] = *(const f16x8_t*)(AH + row * 64 + ((l4 ^ swz) << 4));
        }
#pragma unroll
        for (int nf = 0; nf < 4; ++nf) {
            int rn = wn * 64 + nf * 16 + l15;
            fb[nf] = *(const f16x8_t*)(BH + rn * 64 + ((l4 ^ swz) << 4));
        }
#pragma unroll
        for (int mf = 0; mf < 4; ++mf)
#pragma unroll
            for (int nf = 0; nf < 4; ++nf)
                acc[mf][nf] = __builtin_amdgcn_mfma_f32_16x16x32_f16(fa[mf], fb[nf], acc[mf][nf], 0, 0, 0);
        if (A32 && t + 1 < nt) a32_write(AHn, tid, pre);
        __syncthreads();
    }
    // epilogue: C/D layout col=lane&15, row=(lane>>4)*4+reg
#pragma unroll
    for (int mf = 0; mf < 4; ++mf) {
        int rbase = bm + wm * 64 + mf * 16 + l4 * 4;
#pragma unroll
        for (int nf = 0; nf < 4; ++nf) {
            int col = bn + wn * 64 + nf * 16 + l15;
            if (col >= NCOL) continue;
#pragma unroll
            for (int r = 0; r < 4; ++r) {
                int row = rbase + r;
                if (row < M) {
                    float v = acc[mf][nf][r];
                    if (EPI) {
                        v += bias[col];
                        v = v > 0.f ? v : (expf(v) - 1.f);
                    }
                    if (OUT16) ((_Float16*)Cout)[(size_t)row * ldC + col] = (_Float16)v;
                    else       ((float*)Cout)[(size_t)row * ldC + col] = v;
                }
            }
        }
    }
    if (ELER) {
        const int head = bcol;                 // 128-col tile == one head
        float alv[4], arv[4];
#pragma unroll
        for (int nf = 0; nf < 4; ++nf) {
            int cl = wn * 64 + nf * 16 + l15;  // col within head (0..127)
            alv[nf] = attl[head * OUTF + cl];
            arv[nf] = attr[head * OUTF + cl];
        }
        float pel[4][4], perr[4][4];
#pragma unroll
        for (int mf = 0; mf < 4; ++mf)
#pragma unroll
            for (int r = 0; r < 4; ++r) {
                float se = 0.f, sr = 0.f;
#pragma unroll
                for (int nf = 0; nf < 4; ++nf) {
                    se = fmaf(acc[mf][nf][r], alv[nf], se);
                    sr = fmaf(acc[mf][nf][r], arv[nf], sr);
                }
                pel[mf][r] = se; perr[mf][r] = sr;
            }
        // reduce across the 16-lane column group
#pragma unroll
        for (int off = 1; off < 16; off <<= 1)
#pragma unroll
            for (int mf = 0; mf < 4; ++mf)
#pragma unroll
                for (int r = 0; r < 4; ++r) {
                    pel[mf][r]  += __shfl_xor(pel[mf][r],  off);
                    perr[mf][r] += __shfl_xor(perr[mf][r], off);
                }
        __syncthreads();
        float* red = (float*)lds;              // [128][2] el, then [128][2] er
        if (l15 == 0) {
#pragma unroll
            for (int mf = 0; mf < 4; ++mf)
#pragma unroll
                for (int r = 0; r < 4; ++r) {
                    int rl = wm * 64 + mf * 16 + l4 * 4 + r;
                    red[rl * 2 + wn]       = pel[mf][r];
                    red[256 + rl * 2 + wn] = perr[mf][r];
                }
        }
        __syncthreads();
        if (tid < 128) {
            int row = bm + tid;
            if (row < M) {
                float es = red[tid * 2] + red[tid * 2 + 1];
                float rs = red[256 + tid * 2] + red[256 + tid * 2 + 1];
                elp[row * HEADS + head] = es;
                erp[row * HEADS + head] = rs;
            }
        }
    }
}

// --------------------------- CSR build -------------------------------------
__global__ void hist_kernel(const int* __restrict__ dst, int* __restrict__ deg, int E)
{
    int e = blockIdx.x * 256 + threadIdx.x;
    if (e < E) atomicAdd(&deg[dst[e]], 1);
}

__global__ __launch_bounds__(256) void scan1_kernel(const int* __restrict__ deg,
    int* __restrict__ offs, int* __restrict__ bsum, int N)
{
    __shared__ int buf[256];
    int tid = threadIdx.x;
    int i = blockIdx.x * 256 + tid;
    int v = (i < N) ? deg[i] : 0;
    buf[tid] = v;
    __syncthreads();
#pragma unroll
    for (int off = 1; off < 256; off <<= 1) {
        int t = (tid >= off) ? buf[tid - off] : 0;
        __syncthreads();
        buf[tid] += t;
        __syncthreads();
    }
    if (i < N) offs[i] = buf[tid] - v;
    if (tid == 255) bsum[blockIdx.x] = buf[255];
}

__global__ void scan2_kernel(int* __restrict__ bsum, int nb)
{
    if (threadIdx.x == 0) {
        int acc = 0;
        for (int b = 0; b < nb; ++b) { int t = bsum[b]; bsum[b] = acc; acc += t; }
        bsum[nb] = acc;
    }
}

__global__ void scan3_kernel(int* __restrict__ offs, const int* __restrict__ bsum,
                             int N, int nb)
{
    int i = blockIdx.x * 256 + threadIdx.x;
    if (i < N) offs[i] += bsum[blockIdx.x];
    if (i == 0) offs[N] = bsum[nb];
}

// fill: write src-id directly into the node's slot (psrc = src[csr[...]])
__global__ void fill_kernel(const int* __restrict__ srcv, const int* __restrict__ dstv,
    const int* __restrict__ offs, int* __restrict__ cursor,
    int* __restrict__ psrc, int E)
{
    int e = blockIdx.x * 256 + threadIdx.x;
    if (e < E) {
        int d = dstv[e];
        int p = atomicAdd(&cursor[d], 1);
        psrc[offs[d] + p] = srcv[e];
    }
}

// ------ aggregation v5: barrier-free shuffle-broadcast, 4 nodes/block ------
// One wave per node (4 waves / 256-thr block). Chunk = 32 edges staged in
// registers: lane L stages edge (L&31) for head-pair (L>>5) -- one float2 el
// gather + 2 exp. Weights and source ids broadcast via __shfl (wave lockstep
// => no LDS, no __syncthreads). BW-bound at the L3 gather ceiling (round-3
// post-mortem: occupancy doubling was time-neutral).
__global__ __launch_bounds__(256) void aggregate_kernel(const _Float16* __restrict__ h,
    const int* __restrict__ offs, const int* __restrict__ psrc,
    const float* __restrict__ el, const float* __restrict__ er,
    const float* __restrict__ bias, _Float16* __restrict__ xo, int N)
{
    const int n = blockIdx.x * 4 + (threadIdx.x >> 6);
    if (n >= N) return;
    const int lane = threadIdx.x & 63;
    const int c = lane * 8;
    const int head = lane >> 4;           // reader head (0..3)
    const int hp = lane >> 5;             // staged head-pair (0:h01, 1:h23)
    const int e31 = lane & 31;
    const int sbase = (head >> 1) << 5;   // source-lane base for my head-pair
    const int hsel = head & 1;

    const float2 er2 = *(const float2*)&er[n * HEADS + hp * 2];

    float acc[8];
#pragma unroll
    for (int k = 0; k < 8; ++k) acc[k] = 0.f;
    float ws = 0.f;

    const int beg = offs[n], end = offs[n + 1];
    for (int base = beg; base < end; base += 32) {
        const int cnt = min(32, end - base);
        int idx = base + e31;
        if (e31 >= cnt) idx = beg;        // safe dummy (deg >= 1: self loop)
        const int s = psrc[idx];
        const float2 lv = *(const float2*)&el[s * HEADS + hp * 2];
        float x0 = lv.x + er2.x; x0 = x0 > 0.f ? x0 : 0.2f * x0;
        float x1 = lv.y + er2.y; x1 = x1 > 0.f ? x1 : 0.2f * x1;
        const float wa = expf(x0);        // weight for head hp*2
        const float wb = expf(x1);        // weight for head hp*2+1

        int j = 0;
        for (; j + 4 <= cnt; j += 4) {
            int s0 = __shfl(s, j);     int s1 = __shfl(s, j + 1);
            int s2 = __shfl(s, j + 2); int s3 = __shfl(s, j + 3);
            float a0 = __shfl(wa, sbase + j),     b0 = __shfl(wb, sbase + j);
            float a1 = __shfl(wa, sbase + j + 1), b1 = __shfl(wb, sbase + j + 1);
            float a2 = __shfl(wa, sbase + j + 2), b2 = __shfl(wb, sbase + j + 2);
            float a3 = __shfl(wa, sbase + j + 3), b3 = __shfl(wb, sbase + j + 3);
            float w0 = hsel ? b0 : a0;
            float w1 = hsel ? b1 : a1;
            float w2 = hsel ? b2 : a2;
            float w3 = hsel ? b3 : a3;
            f16x8_t v0 = *(const f16x8_t*)&h[(size_t)s0 * HID + c];
            f16x8_t v1 = *(const f16x8_t*)&h[(size_t)s1 * HID + c];
            f16x8_t v2 = *(const f16x8_t*)&h[(size_t)s2 * HID + c];
            f16x8_t v3 = *(const f16x8_t*)&h[(size_t)s3 * HID + c];
#pragma unroll
            for (int k = 0; k < 8; ++k) {
                acc[k] = fmaf(w0, (float)v0[k], acc[k]);
                acc[k] = fmaf(w1, (float)v1[k], acc[k]);
                acc[k] = fmaf(w2, (float)v2[k], acc[k]);
                acc[k] = fmaf(w3, (float)v3[k], acc[k]);
            }
            ws += w0 + w1 + w2 + w3;
        }
        for (; j < cnt; ++j) {
            int s0 = __shfl(s, j);
            float a0 = __shfl(wa, sbase + j), b0 = __shfl(wb, sbase + j);
            float w0 = hsel ? b0 : a0;
            f16x8_t v0 = *(const f16x8_t*)&h[(size_t)s0 * HID + c];
#pragma unroll
            for (int k = 0; k < 8; ++k) acc[k] = fmaf(w0, (float)v0[k], acc[k]);
            ws += w0;
        }
    }
    float inv = 1.f / ws;
    float4 b0v = *(const float4*)&bias[c];
    float4 b1v = *(const float4*)&bias[c + 4];
    float bb[8] = {b0v.x, b0v.y, b0v.z, b0v.w, b1v.x, b1v.y, b1v.z, b1v.w};
    f16x8_t ov;
#pragma unroll
    for (int k = 0; k < 8; ++k) {
        float r = acc[k] * inv + bb[k];
        r = r > 0.f ? r : (expf(r) - 1.f);
        ov[k] = (_Float16)r;
    }
    *(f16x8_t*)&xo[(size_t)n * HID + c] = ov;
}

// ---------------------------------------------------------------------------
extern "C" void kernel_launch(void* const* d_in, const int* in_sizes, int n_in,
                              void* d_out, int out_size, void* d_ws, size_t ws_size,
                              hipStream_t stream)
{
    const float* feature = (const float*)d_in[0];
    const float* W1  = (const float*)d_in[1];
    const float* al1 = (const float*)d_in[2];
    const float* ar1 = (const float*)d_in[3];
    const float* b1  = (const float*)d_in[4];
    const float* W2  = (const float*)d_in[5];
    const float* al2 = (const float*)d_in[6];
    const float* ar2 = (const float*)d_in[7];
    const float* b2  = (const float*)d_in[8];
    const float* Wfc = (const float*)d_in[9];
    const float* bfc = (const float*)d_in[10];
    const int* src = (const int*)d_in[11];
    const int* dst = (const int*)d_in[12];
    const int N = in_sizes[0] / 1280;
    const int E = in_sizes[11];
    const int nb = (N + 255) / 256;
    float* out = (float*)d_out;

    char* ws = (char*)d_ws;
    size_t off = 0;
    auto alloc = [&](size_t bytes) {
        void* p = ws + off;
        off += (bytes + 255) & ~(size_t)255;
        return p;
    };
    int* deg    = (int*)alloc((size_t)N * 4);
    int* cursor = (int*)alloc((size_t)N * 4);
    int* offs   = (int*)alloc((size_t)(N + 1) * 4);
    int* bsum   = (int*)alloc((size_t)(nb + 1) * 4);
    float* el   = (float*)alloc((size_t)N * HEADS * 4);
    float* er   = (float*)alloc((size_t)N * HEADS * 4);
    int* psrc   = (int*)alloc((size_t)E * 4);
    _Float16* hbuf  = (_Float16*)alloc((size_t)N * HID * 2);
    _Float16* xh    = (_Float16*)alloc((size_t)N * HID * 2);
    _Float16* W1t   = (_Float16*)alloc((size_t)HID * 1280 * 2);
    _Float16* W2t   = (_Float16*)alloc((size_t)HID * HID * 2);
    _Float16* Wft   = (_Float16*)alloc((size_t)64 * HID * 2);

    // CSR build (psrc written directly)
    hipMemsetAsync(deg, 0, (size_t)N * 4, stream);
    hipMemsetAsync(cursor, 0, (size_t)N * 4, stream);
    hist_kernel<<<(E + 255) / 256, 256, 0, stream>>>(dst, deg, E);
    scan1_kernel<<<nb, 256, 0, stream>>>(deg, offs, bsum, N);
    scan2_kernel<<<1, 64, 0, stream>>>(bsum, nb);
    scan3_kernel<<<nb, 256, 0, stream>>>(offs, bsum, N, nb);
    fill_kernel<<<(E + 255) / 256, 256, 0, stream>>>(src, dst, offs, cursor, psrc, E);

    // W prep (fp16, transposed). conv16 is gone: the L1 GEMM stages fp32
    // directly (A32=1) and converts in-register.
    prep_w<<<dim3(1280 / 32, HID / 32), 256, 0, stream>>>(W1, W1t, 1280, HID);
    prep_w<<<dim3(HID / 32, HID / 32), 256, 0, stream>>>(W2, W2t, HID, HID);
    prep_w<<<dim3(HID / 32, 64 / 32), 256, 0, stream>>>(Wfc, Wft, HID, 64);

    const int nrowT = (N + 127) / 128;
    const int nwgG = nrowT * (HID / 128);   // 4 col tiles
    const int nwgF = nrowT;                 // 1 col tile (NCOL=64)
    const int aggB = (N + 3) / 4;

    // ---- layer 1 (GEMM on fp32 feature + fused el/er) ----
    gemm_f16<0, 1, 1, 1><<<nwgG, 256, 0, stream>>>(feature, W1t, nullptr,
                                                   al1, ar1, el, er,
                                                   hbuf, N, 1280, HID, HID,
                                                   HID / 128, nwgG);
    aggregate_kernel<<<aggB, 256, 0, stream>>>(hbuf, offs, psrc, el, er, b1, xh, N);

    // ---- layer 2 ----
    gemm_f16<0, 1, 1, 0><<<nwgG, 256, 0, stream>>>(xh, W2t, nullptr,
                                                   al2, ar2, el, er,
                                                   hbuf, N, HID, HID, HID,
                                                   HID / 128, nwgG);
    aggregate_kernel<<<aggB, 256, 0, stream>>>(hbuf, offs, psrc, el, er, b2, xh, N);

    // ---- fc: MFMA GEMM with fused bias+ELU, fp32 out ----
    gemm_f16<1, 0, 0, 0><<<nwgF, 256, 0, stream>>>(xh, Wft, bfc,
                                                   nullptr, nullptr, nullptr, nullptr,
                                                   out, N, HID, 64, 64,
                                                   1, nwgF);
}